// Round 4
// baseline (90.613 us; speedup 1.0000x reference)
//
#include <hip/hip_runtime.h>

// KAN B-spline layer via MFMA: out[b,o] = sum_k basis[b,k] * W[k,o]
//   basis: (65536 x 768) bf16 built on the fly (K = 64 feats * 12 coeffs)
//   W[k=i*12+c, o] = cp[i,c,o] bf16, pre-packed into MFMA B-fragments (d_ws)
// x: (65536,64) f32, cp: (64,12,64) f32, out: (65536,64) f32
//
// Round 4: double-buffered CHUNK=16 pipeline, 1 barrier/chunk, coalesced x
// loads, conflict-free LDS stride (387 dwords == 3 mod 32), no unions.

typedef short short8 __attribute__((ext_vector_type(8)));
typedef float f32x4 __attribute__((ext_vector_type(4)));
typedef unsigned u32x4 __attribute__((ext_vector_type(4)));

#define NFEAT 64
#define NSTEP 24            // K-steps of 32 (K = 768)
#define CHUNK 16            // rows per chunk (one 16-row MFMA tile)
#define CHUNKS 8
#define RPB   (CHUNK*CHUNKS)   // 128 rows per block
#define THREADS 256
#define RDW   387           // LDS row stride in dwords (774 shorts); 387%32=3 -> <=2-way banks

static __device__ __forceinline__ unsigned bf16rne(float f) {
  unsigned u = __float_as_uint(f);
  return (u + 0x7FFFu + ((u >> 16) & 1u)) >> 16;   // RNE, low 16 bits valid
}

// ---- prep: pack W into per-wave MFMA B-fragments, bf16 ----
// frag element e (0..7) of lane l, step s maps to k = s*32 + (e<4 ? 4g+e : 16+4g+(e-4)),
// g = l>>4. SAME map is used for the A-side in the main kernel -> result invariant
// to the hardware's true intra-step k order (common bijection on both operands).
__global__ __launch_bounds__(256) void prep_wfrag(const float* __restrict__ cp,
                                                  unsigned* __restrict__ wfrag) {
  int id = blockIdx.x * 256 + threadIdx.x;   // 0 .. 24575 (dwords)
  int d  = id & 3;            // dword within frag (elements 2d, 2d+1)
  int l  = (id >> 2) & 63;    // lane
  int id2 = id >> 8;          // 0..95 = nt*24 + s
  int nt = id2 / NSTEP;
  int s  = id2 - nt * NSTEP;
  int g  = l >> 4;
  int o  = nt * 16 + (l & 15);
  int e0 = 2 * d;
  int k0 = s * 32 + ((e0 < 4) ? (4 * g + e0) : (16 + 4 * g + (e0 - 4)));
  unsigned lo = bf16rne(cp[k0 * 64 + o]);
  unsigned hi = bf16rne(cp[(k0 + 1) * 64 + o]);
  wfrag[id] = lo | (hi << 16);
}

// ---- basis eval + dense-12 pack for one x value; writes 6 dwords ----
static __device__ __forceinline__ void eval_pack(float xi, unsigned* __restrict__ dst) {
  xi = fminf(fmaxf(xi, 0.0f), 1.0f);
  float t9 = xi * 9.0f;
  int jj = (int)t9;
  float validf = (jj <= 8) ? 1.0f : 0.0f;   // x==1 -> zero row (ref semantics)
  jj = (jj > 8) ? 8 : jj;
  float fj = (float)jj;
  float u  = t9 - fj;                        // position in interval, [0,1)
  float omu = 1.0f - u;
  float c1  = fminf(fj, 1.0f);
  float c2  = fminf(fj, 2.0f);
  float rdj = 9.0f - fj;
  float d2p = fminf(rdj, 2.0f);
  float d3p = fminf(rdj, 3.0f);
  float invA = (jj == 0) ? 1.0f : 0.5f;                              // kp1-km1
  float invB = (jj == 8) ? 1.0f : 0.5f;                              // kp2-k0
  float invC = (jj == 0) ? 1.0f : ((jj == 1) ? 0.5f : (1.0f/3.0f));  // kp1-km2
  float invD = (jj == 0 || jj == 8) ? 0.5f : (1.0f/3.0f);            // kp2-km1
  float invE = (jj >= 7) ? ((jj == 8) ? 1.0f : 0.5f) : (1.0f/3.0f);  // kp3-k0
  float xkm1 = u + c1, xkm2 = u + c2;
  float k2x = d2p - u, k3x = d3p - u;
  float t0 = omu * invA;
  float A0 = omu * t0;
  float s1 = xkm1 * t0;
  float t1 = u * invB;
  float A1 = fmaf(k2x, t1, s1);
  float A2 = u * t1;
  float u0 = A0 * invC;
  float B0 = omu * u0;
  float s2 = xkm2 * u0;
  float u1 = A1 * invD;
  float B1 = fmaf(k2x, u1, s2);
  float s3 = xkm1 * u1;
  float u2 = A2 * invE;
  float B2 = fmaf(k3x, u2, s3);
  float B3 = u * u2;
  B0 *= validf; B1 *= validf; B2 *= validf; B3 *= validf;

  unsigned b0 = bf16rne(B0), b1 = bf16rne(B1), b2 = bf16rne(B2), b3 = bf16rne(B3);
  unsigned p01 = b0 | (b1 << 16);
  unsigned p23 = b2 | (b3 << 16);
  unsigned O0 = p01 << 16;
  unsigned O1 = (p01 >> 16) | (p23 << 16);
  unsigned O2 = p23 >> 16;
  int e2 = jj >> 1;
  bool odd = (jj & 1) != 0;
  #pragma unroll
  for (int q = 0; q < 6; ++q) {
    unsigned ve = (q == e2) ? p01 : ((q == e2 + 1) ? p23 : 0u);
    unsigned vo = (q == e2) ? O0 : ((q == e2 + 1) ? O1 : ((q == e2 + 2) ? O2 : 0u));
    dst[q] = odd ? vo : ve;
  }
}

__global__ __launch_bounds__(THREADS) void kan_mfma(const float* __restrict__ x,
                                                    const unsigned* __restrict__ wfrag,
                                                    float* __restrict__ out) {
  __shared__ unsigned bsd[2][CHUNK * RDW];     // 2 x 24768 B = 49536 B
  const int tid  = threadIdx.x;
  const int lane = tid & 63;
  const int w    = tid >> 6;            // wave id = n-tile (16 output cols)
  const long rowBase = (long)blockIdx.x * RPB;

  // ---- B fragments for this wave's 16 columns: all K in registers (96 VGPRs) ----
  short8 bfr[NSTEP];
  {
    const short8* wp = (const short8*)wfrag + (w * NSTEP * 64 + lane);
    #pragma unroll
    for (int s = 0; s < NSTEP; ++s) bfr[s] = wp[s * 64];
  }

  // build-phase mapping: thread -> (row br, feats bi0..bi0+3), coalesced float4 x load
  const int br  = tid >> 4;             // 0..15
  const int bi0 = (tid & 15) * 4;       // 0,4,...,60
  // mfma-phase mapping
  const int m = lane & 15, g = lane >> 4;

  // ---- prologue: build chunk 0 into buffer 0 ----
  {
    const float4 xv = *(const float4*)(x + (rowBase + br) * 64 + bi0);
    float xs4[4] = {xv.x, xv.y, xv.z, xv.w};
    #pragma unroll
    for (int e = 0; e < 4; ++e)
      eval_pack(xs4[e], &bsd[0][br * RDW + (bi0 + e) * 6]);
  }
  __syncthreads();

  for (int c = 0; c < CHUNKS; ++c) {
    const int cur = c & 1;

    // hoist next chunk's x load (HBM latency hides under MFMA phase)
    float xs4[4];
    if (c < CHUNKS - 1) {
      const float4 xv = *(const float4*)(x + (rowBase + (c + 1) * CHUNK + br) * 64 + bi0);
      xs4[0] = xv.x; xs4[1] = xv.y; xs4[2] = xv.z; xs4[3] = xv.w;
    }

    // ---- MFMA over K=768 for chunk c ----
    f32x4 acc = {0.0f, 0.0f, 0.0f, 0.0f};
    {
      const short* base = (const short*)&bsd[cur][0] + m * (2 * RDW) + g * 4;
      #pragma unroll
      for (int s = 0; s < NSTEP; ++s) {
        const unsigned* pa = (const unsigned*)(base + s * 32);
        const unsigned* pb = (const unsigned*)(base + s * 32 + 16);
        u32x4 q = { pa[0], pa[1], pb[0], pb[1] };
        acc = __builtin_amdgcn_mfma_f32_16x16x32_bf16(
            __builtin_bit_cast(short8, q), bfr[s], acc, 0, 0, 0);
      }
    }
    // coalesced-ish stores: 16 consecutive dwords per 16-lane group
    {
      float* op = out + (rowBase + c * CHUNK + g * 4) * 64 + w * 16 + m;
      #pragma unroll
      for (int j = 0; j < 4; ++j) op[j * 64] = acc[j];
    }

    // ---- build chunk c+1 into the other buffer (overlaps other blocks' MFMA) ----
    if (c < CHUNKS - 1) {
      #pragma unroll
      for (int e = 0; e < 4; ++e)
        eval_pack(xs4[e], &bsd[cur ^ 1][br * RDW + (bi0 + e) * 6]);
    }
    __syncthreads();
  }
}

extern "C" void kernel_launch(void* const* d_in, const int* in_sizes, int n_in,
                              void* d_out, int out_size, void* d_ws, size_t ws_size,
                              hipStream_t stream) {
  const float* x  = (const float*)d_in[0];
  const float* cp = (const float*)d_in[1];
  float* out = (float*)d_out;
  unsigned* wfrag = (unsigned*)d_ws;   // 24576 dwords = 96 KB

  hipLaunchKernelGGL(prep_wfrag, dim3(96), dim3(256), 0, stream, cp, wfrag);
  const int rows = in_sizes[0] / NFEAT;          // 65536
  hipLaunchKernelGGL(kan_mfma, dim3(rows / RPB), dim3(THREADS), 0, stream,
                     x, wfrag, out);
}